// Round 12
// baseline (99.904 us; speedup 1.0000x reference)
//
#include <hip/hip_runtime.h>
#include <hip/hip_bf16.h>
#include <math.h>

// ---- constants mirroring the reference ----
#define TWO_PI_D 6.283185307179586
constexpr int   NOFF  = 32768;
constexpr int   NSAMP = 128;
constexpr int   NRF   = 4;
constexpr int   NSTEP = NRF * NSAMP;   // 512
constexpr float DT    = 3.9e-05f;
constexpr double DTD  = 3.9e-05;
constexpr float R1A   = 1.0f / 1.3f;
constexpr float R2A   = 1.0f / 0.075f;
constexpr float R1B   = 1.0f;
constexpr float R2B   = 30.0f;
constexpr float KBv   = 200.0f;
constexpr float FBv   = 0.01f;
constexpr float KAv   = FBv * KBv;     // 2.0
constexpr float DWB   = 447.0f;

struct AccPhD { double a[8]; };        // [sim][rf_block] accumulated phase (f64)

// Per-(sim,step) EXACT RF rotation R = exp(W*DT): Rodrigues about in-plane
// axis n = (-cos ph, -sin ph, 0), angle th = w1*DT. 6 distinct coeffs.
// Stored as 8 floats: [r00,r01,r02,r12][r11,r22,0,0].
__global__ void rot_table_kernel(const float* __restrict__ amps,
                                 const float* __restrict__ phases,
                                 AccPhD acc, float4* __restrict__ rt4) {
    int tid = blockIdx.x * blockDim.x + threadIdx.x;   // 0..1023
    if (tid >= 2 * NSTEP) return;
    int sim = tid >> 9;
    int idx = tid & (NSTEP - 1);
    int r   = idx >> 7;
    double ph = -(double)phases[idx] - acc.a[sim * 4 + r];
    double w1 = TWO_PI_D * 42.577 * (double)amps[idx];
    double th = w1 * DTD;
    double sn = sin(th), cs = cos(th), Cc = 1.0 - cs;
    double nx = -cos(ph), ny = -sin(ph);
    float r00 = (float)(cs + nx * nx * Cc);
    float r01 = (float)(nx * ny * Cc);
    float r02 = (float)(ny * sn);
    float r12 = (float)(-nx * sn);
    float r11 = (float)(cs + ny * ny * Cc);
    float r22 = (float)cs;
    rt4[2 * tid]     = make_float4(r00, r01, r02, r12);
    rt4[2 * tid + 1] = make_float4(r11, r22, 0.0f, 0.0f);
}

__global__ void init_kernel(unsigned int* g) {
    if (threadIdx.x < 2) g[threadIdx.x] = 0u;
}

__global__ __launch_bounds__(256)
__attribute__((amdgpu_waves_per_eu(1, 1)))   // grid is exactly 1 wave/SIMD
void bmc_kernel(
        const float* __restrict__ offsets,
        const float* __restrict__ m_init,
        const float* __restrict__ rt,
        unsigned int* __restrict__ gmax) {
    // sim derived from blockIdx ONLY -> provably wave-uniform -> the rotation
    // table loads scalarize to s_load (SMEM pipe, SGPR dest): no 64-lane
    // broadcast replication through L1, no VALU issue slots for loads.
    int sim = (int)(blockIdx.x >> 7);              // 128 blocks per sim
    sim = __builtin_amdgcn_readfirstlane(sim);     // belt-and-braces uniformity
    int o = (int)(blockIdx.x * 256 + threadIdx.x) & (NOFF - 1);

    const float TP  = (float)TWO_PI_D;
    float rf  = sim ? -200.0f : 200.0f;
    float off = offsets[o];
    float dwa = TP * (off - rf);
    float dwb = TP * ((off + DWB) - rf);

    // ---- one-time: Eh = exp(D~ * DT/2) (augmented 6x7, order-9 Taylor),
    //      then Ef = Eh*Eh (full step). D~ = [[D, b],[0,0]], D = drift. ----
    const float h     = 0.5f * DT;
    const float ca_h  = -(R2A + KAv) * h;
    const float cb_h  = -(R1A + KAv) * h;
    const float cc_h  = -(R2B + KBv) * h;
    const float cd_h  = -(R1B + KBv) * h;
    const float ka_h  = KAv * h, kb_h = KBv * h;
    const float dwa_h = dwa * h, dwb_h = dwb * h;
    const float b2_h  = R1A * h, b5_h = R1B * FBv * h;

    float Eh[6][7], U[6][7];
#pragma unroll
    for (int i = 0; i < 6; ++i)
#pragma unroll
        for (int j = 0; j < 7; ++j) {
            float v = (i == j) ? 1.0f : 0.0f;
            Eh[i][j] = v; U[i][j] = v;
        }
#pragma unroll
    for (int k = 1; k <= 9; ++k) {
        const float rk = 1.0f / (float)k;
        float N[6][7];
#pragma unroll
        for (int i = 0; i < 6; ++i) {
            N[i][0] = U[i][0] * ca_h  - U[i][1] * dwa_h + U[i][3] * ka_h;
            N[i][1] = U[i][0] * dwa_h + U[i][1] * ca_h  + U[i][4] * ka_h;
            N[i][2] = U[i][2] * cb_h  + U[i][5] * ka_h;
            N[i][3] = U[i][0] * kb_h  + U[i][3] * cc_h  - U[i][4] * dwb_h;
            N[i][4] = U[i][1] * kb_h  + U[i][3] * dwb_h + U[i][4] * cc_h;
            N[i][5] = U[i][2] * kb_h  + U[i][5] * cd_h;
            N[i][6] = U[i][2] * b2_h  + U[i][5] * b5_h;
        }
#pragma unroll
        for (int i = 0; i < 6; ++i)
#pragma unroll
            for (int j = 0; j < 7; ++j) {
                U[i][j] = N[i][j] * rk;
                Eh[i][j] += U[i][j];
            }
    }
    float Ef[6][7];
#pragma unroll
    for (int i = 0; i < 6; ++i)
#pragma unroll
        for (int j = 0; j < 7; ++j) {
            float s = (j == 6) ? Eh[i][6] : 0.0f;
#pragma unroll
            for (int k2 = 0; k2 < 6; ++k2) s += Eh[i][k2] * Eh[k2][j];
            Ef[i][j] = s;
        }

    // Named scalar copies of Ef (per-thread values -> VGPRs)
    const float E00=Ef[0][0],E01=Ef[0][1],E02=Ef[0][2],E03=Ef[0][3],E04=Ef[0][4],E05=Ef[0][5],Q0=Ef[0][6];
    const float E10=Ef[1][0],E11=Ef[1][1],E12=Ef[1][2],E13=Ef[1][3],E14=Ef[1][4],E15=Ef[1][5],Q1=Ef[1][6];
    const float E20=Ef[2][0],E21=Ef[2][1],E22=Ef[2][2],E23=Ef[2][3],E24=Ef[2][4],E25=Ef[2][5],Q2=Ef[2][6];
    const float E30=Ef[3][0],E31=Ef[3][1],E32=Ef[3][2],E33=Ef[3][3],E34=Ef[3][4],E35=Ef[3][5],Q3=Ef[3][6];
    const float E40=Ef[4][0],E41=Ef[4][1],E42=Ef[4][2],E43=Ef[4][3],E44=Ef[4][4],E45=Ef[4][5],Q4=Ef[4][6];
    const float E50=Ef[5][0],E51=Ef[5][1],E52=Ef[5][2],E53=Ef[5][3],E54=Ef[5][4],E55=Ef[5][5],Q5=Ef[5][6];

    // ---- pre: m = Eh * [m_init; 1]  (enter the half-shifted Strang frame).
    // Final sample also taken in the half-frame: |Mxy| differs by <= ~3e-4
    // relative (decay/exchange over DT/2; rotation is norm-preserving).
    float x0 = m_init[0], x1 = m_init[1], x2 = m_init[2];
    float x3 = m_init[3], x4 = m_init[4], x5 = m_init[5];
    float mi[6];
#pragma unroll
    for (int i = 0; i < 6; ++i)
        mi[i] = Eh[i][6] + Eh[i][0]*x0 + Eh[i][1]*x1 + Eh[i][2]*x2
                         + Eh[i][3]*x3 + Eh[i][4]*x4 + Eh[i][5]*x5;
    float m0 = mi[0], m1 = mi[1], m2 = mi[2], m3 = mi[3], m4 = mi[4], m5 = mi[5];
    float lmax = 0.0f;

    // ---- per step (SCALAR VALU): m <- Ef * (R(s) * m) + q.
    // Rotation: 6 parallel depth-3 FMA chains (18 FMA).
    // Drift: 6 parallel serial-6-FMA rows seeded with q (36 FMA).
    // Rotation coeffs come from SGPRs (1 SGPR operand per v_fma: legal).
#define FULL_STEP(ta, tb)                                                      \
    {                                                                          \
        const float r00 = (ta).x, r01 = (ta).y, r02 = (ta).z, r12 = (ta).w;    \
        const float r11 = (tb).x, r22 = (tb).y;                                \
        float xa = fmaf(r00, m0, fmaf(r01, m1,  r02 * m2));                    \
        float ya = fmaf(r01, m0, fmaf(r11, m1,  r12 * m2));                    \
        float za = fmaf(-r02, m0, fmaf(-r12, m1, r22 * m2));                   \
        float xb = fmaf(r00, m3, fmaf(r01, m4,  r02 * m5));                    \
        float yb = fmaf(r01, m3, fmaf(r11, m4,  r12 * m5));                    \
        float zb = fmaf(-r02, m3, fmaf(-r12, m4, r22 * m5));                   \
        m0 = fmaf(E05, zb, fmaf(E04, yb, fmaf(E03, xb, fmaf(E02, za, fmaf(E01, ya, fmaf(E00, xa, Q0)))))); \
        m1 = fmaf(E15, zb, fmaf(E14, yb, fmaf(E13, xb, fmaf(E12, za, fmaf(E11, ya, fmaf(E10, xa, Q1)))))); \
        m2 = fmaf(E25, zb, fmaf(E24, yb, fmaf(E23, xb, fmaf(E22, za, fmaf(E21, ya, fmaf(E20, xa, Q2)))))); \
        m3 = fmaf(E35, zb, fmaf(E34, yb, fmaf(E33, xb, fmaf(E32, za, fmaf(E31, ya, fmaf(E30, xa, Q3)))))); \
        m4 = fmaf(E45, zb, fmaf(E44, yb, fmaf(E43, xb, fmaf(E42, za, fmaf(E41, ya, fmaf(E40, xa, Q4)))))); \
        m5 = fmaf(E55, zb, fmaf(E54, yb, fmaf(E53, xb, fmaf(E52, za, fmaf(E51, ya, fmaf(E50, xa, Q5)))))); \
        lmax = fmaxf(lmax, fmaf(m0, m0, m1 * m1));                             \
    }

    // Table pointer is uniform (sim from blockIdx) -> s_load path.
    const float4* __restrict__ rtu = (const float4*)rt + (size_t)sim * NSTEP * 2;
    // A/B double-buffer, 8 steps (=16 float4) per iteration.
    float4 a0 = rtu[0], a1 = rtu[1], a2 = rtu[2], a3 = rtu[3];
    float4 a4 = rtu[4], a5 = rtu[5], a6 = rtu[6], a7 = rtu[7];
    float4 b0 = rtu[8], b1 = rtu[9], b2 = rtu[10], b3 = rtu[11];
    float4 b4 = rtu[12], b5 = rtu[13], b6 = rtu[14], b7 = rtu[15];
#pragma unroll 1
    for (int j = 0; j < 63; ++j) {               // steps 0..503
        int nb = (j + 1) * 16;                   // 16 float4 consumed per iter
        FULL_STEP(a0, a1)                        // steps 8j .. 8j+3
        FULL_STEP(a2, a3)
        FULL_STEP(a4, a5)
        FULL_STEP(a6, a7)
        a0 = rtu[nb+0]; a1 = rtu[nb+1]; a2 = rtu[nb+2]; a3 = rtu[nb+3];
        a4 = rtu[nb+4]; a5 = rtu[nb+5]; a6 = rtu[nb+6]; a7 = rtu[nb+7];
        FULL_STEP(b0, b1)                        // steps 8j+4 .. 8j+7
        FULL_STEP(b2, b3)
        FULL_STEP(b4, b5)
        FULL_STEP(b6, b7)
        b0 = rtu[nb+8];  b1 = rtu[nb+9];  b2 = rtu[nb+10]; b3 = rtu[nb+11];
        b4 = rtu[nb+12]; b5 = rtu[nb+13]; b6 = rtu[nb+14]; b7 = rtu[nb+15];
    }
    // after loop: A = steps 504..507, B = steps 508..511
    FULL_STEP(a0, a1)
    FULL_STEP(a2, a3)
    FULL_STEP(a4, a5)
    FULL_STEP(a6, a7)
    FULL_STEP(b0, b1)
    FULL_STEP(b2, b3)
    FULL_STEP(b4, b5)
    FULL_STEP(b6, b7)                            // step 511; half-frame sample
#undef FULL_STEP

    // wave-64 max reduce, then one atomic per wave (sim uniform per wave)
    for (int d = 32; d >= 1; d >>= 1)
        lmax = fmaxf(lmax, __shfl_xor(lmax, d, 64));
    if ((threadIdx.x & 63) == 0)
        atomicMax(gmax + sim, __float_as_uint(lmax));   // all values >= 0

    (void)NSAMP;
}

__global__ void finalize_kernel(const unsigned int* __restrict__ gmax,
                                float* __restrict__ out) {
    int i = threadIdx.x;
    if (i < 2) out[i] = sqrtf(__uint_as_float(gmax[i]));   // float32 output
}

extern "C" void kernel_launch(void* const* d_in, const int* in_sizes, int n_in,
                              void* d_out, int out_size, void* d_ws, size_t ws_size,
                              hipStream_t stream) {
    const float* amps    = (const float*)d_in[0];   // (4,128)
    const float* phases  = (const float*)d_in[1];   // (4,128)
    const float* offsets = (const float*)d_in[2];   // (32768,)
    const float* m_init  = (const float*)d_in[3];   // (6,)
    float* out           = (float*)d_out;           // (2,) float32

    unsigned int* gmax = (unsigned int*)d_ws;                 // 2 slots
    float* rt = (float*)((char*)d_ws + 256);                  // 2*512*8 floats = 32 KB

    // Python-semantics accumulated phase per (sim, rf block), in f64
    AccPhD acc;
    for (int s = 0; s < 2; ++s) {
        double rfo  = s ? -200.0 : 200.0;
        double accp = 0.0;
        for (int r = 0; r < NRF; ++r) {
            acc.a[s * 4 + r] = accp;
            double pd = fmod(3.9e-05 * 128.0 * 360.0 * rfo, 360.0);
            if (pd < 0.0) pd += 360.0;      // Python % semantics
            accp += pd / 180.0 * M_PI;
        }
    }

    init_kernel<<<1, 64, 0, stream>>>(gmax);
    rot_table_kernel<<<4, 256, 0, stream>>>(amps, phases, acc, (float4*)rt);
    bmc_kernel<<<(2 * NOFF) / 256, 256, 0, stream>>>(offsets, m_init, rt, gmax);
    finalize_kernel<<<1, 64, 0, stream>>>(gmax, out);
}

// Round 13
// 73.291 us; speedup vs baseline: 1.3631x; 1.3631x over previous
//
#include <hip/hip_runtime.h>
#include <hip/hip_bf16.h>
#include <math.h>

// ---- constants mirroring the reference ----
#define TWO_PI_D 6.283185307179586
constexpr int   NOFF  = 32768;
constexpr int   NSAMP = 128;
constexpr int   NRF   = 4;
constexpr int   NSTEP = NRF * NSAMP;   // 512
constexpr float DT    = 3.9e-05f;
constexpr double DTD  = 3.9e-05;
constexpr float R1A   = 1.0f / 1.3f;
constexpr float R2A   = 1.0f / 0.075f;
constexpr float R1B   = 1.0f;
constexpr float R2B   = 30.0f;
constexpr float KBv   = 200.0f;
constexpr float FBv   = 0.01f;
constexpr float KAv   = FBv * KBv;     // 2.0
constexpr float DWB   = 447.0f;

typedef float f32x16 __attribute__((ext_vector_type(16)));

// Wave-uniform table load through the SCALAR pipe: SGPR dest, no per-lane
// replication, no VALU slots, counted by lgkmcnt (SMEM).
#define SLOAD16(dst, p, OFF) \
    asm volatile("s_load_dwordx16 %0, %1, " #OFF : "=s"(dst) : "s"(p))
// lgkmcnt(0) wait with data-dependence fencing: consumers of a/b depend on
// this asm, so compute cannot be hoisted above it (r11-proven pattern).
#define LWAIT(a, b) \
    asm volatile("s_waitcnt lgkmcnt(0)" : "+s"(a), "+s"(b))

struct AccPhD { double a[8]; };        // [sim][rf_block] accumulated phase (f64)

// Per-(sim,step) EXACT RF rotation R = exp(W*DT): Rodrigues about in-plane
// axis n = (-cos ph, -sin ph, 0), angle th = w1*DT. 6 distinct coeffs.
// Stored as 8 floats/step: [r00,r01,r02,r12][r11,r22,0,0].
__global__ void rot_table_kernel(const float* __restrict__ amps,
                                 const float* __restrict__ phases,
                                 AccPhD acc, float4* __restrict__ rt4) {
    int tid = blockIdx.x * blockDim.x + threadIdx.x;   // 0..1023
    if (tid >= 2 * NSTEP) return;
    int sim = tid >> 9;
    int idx = tid & (NSTEP - 1);
    int r   = idx >> 7;
    double ph = -(double)phases[idx] - acc.a[sim * 4 + r];
    double w1 = TWO_PI_D * 42.577 * (double)amps[idx];
    double th = w1 * DTD;
    double sn = sin(th), cs = cos(th), Cc = 1.0 - cs;
    double nx = -cos(ph), ny = -sin(ph);
    rt4[2 * tid]     = make_float4((float)(cs + nx * nx * Cc),
                                   (float)(nx * ny * Cc),
                                   (float)(ny * sn),
                                   (float)(-nx * sn));
    rt4[2 * tid + 1] = make_float4((float)(cs + ny * ny * Cc),
                                   (float)cs, 0.0f, 0.0f);
}

__global__ void init_kernel(unsigned int* g) {
    if (threadIdx.x < 2) g[threadIdx.x] = 0u;
}

__global__ __launch_bounds__(256)
__attribute__((amdgpu_waves_per_eu(1, 1)))
void bmc_kernel(
        const float* __restrict__ offsets,
        const float* __restrict__ m_init,
        const float* __restrict__ rt,
        unsigned int* __restrict__ gmax) {
    int sim = (int)(blockIdx.x >> 7);              // 128 blocks per sim
    sim = __builtin_amdgcn_readfirstlane(sim);     // provably wave-uniform
    int o = (int)(blockIdx.x * 256 + threadIdx.x) & (NOFF - 1);

    const float TP  = (float)TWO_PI_D;
    float rf  = sim ? -200.0f : 200.0f;
    float off = offsets[o];
    float dwa = TP * (off - rf);
    float dwb = TP * ((off + DWB) - rf);

    // ---- one-time: drift exponential, EXACTLY block-diagonalized ----
    // Transverse (m0,m1,m3,m4): za=m0+i*m1, zb=m3+i*m4,
    //   d[za;zb]/dt = [[ca-i*dwa, kb],[ka, cc-i*dwb]] [za;zb]   (2x2 complex)
    // Longitudinal (m2,m5): dv/dt = [[cbv, kb],[ka, cdv]] v + (b2, b5)
    const float h   = 0.5f * DT;
    const float ca  = -(R2A + KAv), cbv = -(R1A + KAv);
    const float cc  = -(R2B + KBv), cdv = -(R1B + KBv);

    // Taylor-9 of the HALF-step transverse exp (complex 2x2): S = exp(Th)
    float SAr=1, SAi=0, SBr=0, SBi=0, SCr=0, SCi=0, SDr=1, SDi=0;
    {
        const float har = ca * h,  hai = -dwa * h;
        const float hbr = KBv * h;                  // imag 0
        const float hcr = KAv * h;                  // imag 0
        const float hdr = cc * h,  hdi = -dwb * h;
        float UAr=1, UAi=0, UBr=0, UBi=0, UCr=0, UCi=0, UDr=1, UDi=0;
#pragma unroll
        for (int k = 1; k <= 9; ++k) {
            const float rk = 1.0f / (float)k;
            float NAr = UAr*har - UAi*hai + UBr*hcr;
            float NAi = UAr*hai + UAi*har + UBi*hcr;
            float NBr = UAr*hbr + UBr*hdr - UBi*hdi;
            float NBi = UAi*hbr + UBr*hdi + UBi*hdr;
            float NCr = UCr*har - UCi*hai + UDr*hcr;
            float NCi = UCr*hai + UCi*har + UDi*hcr;
            float NDr = UCr*hbr + UDr*hdr - UDi*hdi;
            float NDi = UCi*hbr + UDr*hdi + UDi*hdr;
            UAr = NAr*rk; UAi = NAi*rk; UBr = NBr*rk; UBi = NBi*rk;
            UCr = NCr*rk; UCi = NCi*rk; UDr = NDr*rk; UDi = NDi*rk;
            SAr += UAr; SAi += UAi; SBr += UBr; SBi += UBi;
            SCr += UCr; SCi += UCi; SDr += UDr; SDi += UDi;
        }
    }
    // FULL-step transverse: F = S*S
    const float trr = SAr + SDr, tri = SAi + SDi;
    const float bcr = SBr*SCr - SBi*SCi, bci = SBr*SCi + SBi*SCr;
    const float Ar = SAr*SAr - SAi*SAi + bcr, Ai = 2.0f*SAr*SAi + bci;
    const float Br = SBr*trr - SBi*tri,       Bi = SBr*tri + SBi*trr;
    const float Cr = SCr*trr - SCi*tri,       Ci = SCr*tri + SCi*trr;
    const float Dr = SDr*SDr - SDi*SDi + bcr, Di = 2.0f*SDr*SDi + bci;

    // Taylor-9 of HALF-step longitudinal augmented exp (2x3)
    float s00=1, s01=0, s02=0, s10=0, s11=1, s12=0;
    {
        const float l00 = cbv*h, l01 = KBv*h, l02 = R1A*h;
        const float l10 = KAv*h, l11 = cdv*h, l12 = R1B*FBv*h;
        float u00=1, u01=0, u02=0, u10=0, u11=1, u12=0;
#pragma unroll
        for (int k = 1; k <= 9; ++k) {
            const float rk = 1.0f / (float)k;
            float n00 = u00*l00 + u01*l10;
            float n01 = u00*l01 + u01*l11;
            float n02 = u00*l02 + u01*l12;
            float n10 = u10*l00 + u11*l10;
            float n11 = u10*l01 + u11*l11;
            float n12 = u10*l02 + u11*l12;
            u00 = n00*rk; u01 = n01*rk; u02 = n02*rk;
            u10 = n10*rk; u11 = n11*rk; u12 = n12*rk;
            s00 += u00; s01 += u01; s02 += u02;
            s10 += u10; s11 += u11; s12 += u12;
        }
    }
    // FULL-step longitudinal: E_L = S2, q = S*qh + qh
    const float eL00 = s00*s00 + s01*s10, eL01 = s00*s01 + s01*s11;
    const float eL10 = s10*s00 + s11*s10, eL11 = s10*s01 + s11*s11;
    const float qL0  = s00*s02 + s01*s12 + s02;
    const float qL1  = s10*s02 + s11*s12 + s12;

    // ---- pre: enter the half-shifted Strang frame: m = Eh * m_init ----
    float x0i = m_init[0], y0i = m_init[1], z0i = m_init[2];
    float x1i = m_init[3], y1i = m_init[4], z1i = m_init[5];
    float m0x = SAr*x0i - SAi*y0i + SBr*x1i - SBi*y1i;
    float m0y = SAr*y0i + SAi*x0i + SBr*y1i + SBi*x1i;
    float m1x = SCr*x0i - SCi*y0i + SDr*x1i - SDi*y1i;
    float m1y = SCr*y0i + SCi*x0i + SDr*y1i + SDi*x1i;
    float m0z = s00*z0i + s01*z1i + s02;
    float m1z = s10*z0i + s11*z1i + s12;
    float lmax = 0.0f;

    // ---- per step: rotation (SGPR coeffs) then split drift. 41 VALU. ----
#define FULL_STEP(g, s)                                                        \
    {                                                                          \
        const float r00 = (g)[8*(s)+0], r01 = (g)[8*(s)+1];                    \
        const float r02 = (g)[8*(s)+2], r12 = (g)[8*(s)+3];                    \
        const float r11 = (g)[8*(s)+4], r22 = (g)[8*(s)+5];                    \
        float xa = fmaf(r00, m0x, fmaf(r01, m0y,  r02 * m0z));                 \
        float ya = fmaf(r01, m0x, fmaf(r11, m0y,  r12 * m0z));                 \
        float za = fmaf(-r02, m0x, fmaf(-r12, m0y, r22 * m0z));                \
        float xb = fmaf(r00, m1x, fmaf(r01, m1y,  r02 * m1z));                 \
        float yb = fmaf(r01, m1x, fmaf(r11, m1y,  r12 * m1z));                 \
        float zb = fmaf(-r02, m1x, fmaf(-r12, m1y, r22 * m1z));                \
        m0x = fmaf(Ar, xa, fmaf(-Ai, ya, fmaf(Br, xb, -Bi * yb)));             \
        m0y = fmaf(Ar, ya, fmaf( Ai, xa, fmaf(Br, yb,  Bi * xb)));             \
        m1x = fmaf(Cr, xa, fmaf(-Ci, ya, fmaf(Dr, xb, -Di * yb)));             \
        m1y = fmaf(Cr, ya, fmaf( Ci, xa, fmaf(Dr, yb,  Di * xb)));             \
        m0z = fmaf(eL00, za, fmaf(eL01, zb, qL0));                             \
        m1z = fmaf(eL10, za, fmaf(eL11, zb, qL1));                             \
        lmax = fmaxf(lmax, fmaf(m0x, m0x, m0y * m0y));                         \
    }
#define COMPUTE4(G0, G1) \
    FULL_STEP(G0, 0) FULL_STEP(G0, 1) FULL_STEP(G1, 0) FULL_STEP(G1, 1)

    // SGPR double buffer: group = 4 steps = 32 floats = 2 x s_load_dwordx16.
    // Schedule keeps EXACTLY ONE buffer outstanding at each lgkmcnt(0), with
    // a 4-step compute window covering SMEM latency.
    const float* p = rt + (size_t)sim * NSTEP * 8;   // uniform -> SGPR pair
    f32x16 A0, A1, B0, B1;
    SLOAD16(A0, p, 0x0); SLOAD16(A1, p, 0x40);
    LWAIT(A0, A1);
    SLOAD16(B0, p, 0x80); SLOAD16(B1, p, 0xC0);
#pragma unroll 1
    for (int j = 0; j < 63; ++j) {        // 8 steps per iter: groups 2j, 2j+1
        COMPUTE4(A0, A1)                  // window for B's in-flight loads
        LWAIT(B0, B1);
        SLOAD16(A0, p, 0x100); SLOAD16(A1, p, 0x140);   // group 2j+2
        COMPUTE4(B0, B1)                  // window for A's loads
        LWAIT(A0, A1);
        SLOAD16(B0, p, 0x180); SLOAD16(B1, p, 0x1C0);   // group 2j+3
        p += 64;                          // advance 2 groups (256 B)
    }
    COMPUTE4(A0, A1)                      // steps 504..507
    LWAIT(B0, B1);
    COMPUTE4(B0, B1)                      // steps 508..511 (half-frame sample)
#undef COMPUTE4
#undef FULL_STEP

    // wave-64 max reduce, then one atomic per wave (sim uniform per wave)
    for (int d = 32; d >= 1; d >>= 1)
        lmax = fmaxf(lmax, __shfl_xor(lmax, d, 64));
    if ((threadIdx.x & 63) == 0)
        atomicMax(gmax + sim, __float_as_uint(lmax));   // all values >= 0

    (void)NSAMP;
}

__global__ void finalize_kernel(const unsigned int* __restrict__ gmax,
                                float* __restrict__ out) {
    int i = threadIdx.x;
    if (i < 2) out[i] = sqrtf(__uint_as_float(gmax[i]));   // float32 output
}

extern "C" void kernel_launch(void* const* d_in, const int* in_sizes, int n_in,
                              void* d_out, int out_size, void* d_ws, size_t ws_size,
                              hipStream_t stream) {
    const float* amps    = (const float*)d_in[0];   // (4,128)
    const float* phases  = (const float*)d_in[1];   // (4,128)
    const float* offsets = (const float*)d_in[2];   // (32768,)
    const float* m_init  = (const float*)d_in[3];   // (6,)
    float* out           = (float*)d_out;           // (2,) float32

    unsigned int* gmax = (unsigned int*)d_ws;                 // 2 slots
    float* rt = (float*)((char*)d_ws + 256);                  // 2*512*8 floats = 32 KB

    // Python-semantics accumulated phase per (sim, rf block), in f64
    AccPhD acc;
    for (int s = 0; s < 2; ++s) {
        double rfo  = s ? -200.0 : 200.0;
        double accp = 0.0;
        for (int r = 0; r < NRF; ++r) {
            acc.a[s * 4 + r] = accp;
            double pd = fmod(3.9e-05 * 128.0 * 360.0 * rfo, 360.0);
            if (pd < 0.0) pd += 360.0;      // Python % semantics
            accp += pd / 180.0 * M_PI;
        }
    }

    init_kernel<<<1, 64, 0, stream>>>(gmax);
    rot_table_kernel<<<4, 256, 0, stream>>>(amps, phases, acc, (float4*)rt);
    bmc_kernel<<<(2 * NOFF) / 256, 256, 0, stream>>>(offsets, m_init, rt, gmax);
    finalize_kernel<<<1, 64, 0, stream>>>(gmax, out);
}